// Round 1
// baseline (5508.067 us; speedup 1.0000x reference)
//
#include <hip/hip_runtime.h>
#include <math.h>

#define GROUPS 32
#define CG 16
#define HH 56
#define WW 56
#define HW (HH*WW)          // 3136
#define BG 1024             // B*GROUPS
#define EPS 1e-5f

// ---------------------------------------------------------------------------
// Kernel A: per-instance directional pooling -> 1x1 channel mix -> sigmoid
// gates (xh, xw), then per-channel mean/var of t = gx*xh*xw  ->  scale/shift
// for the instance-norm branch. One block per bg-instance.
// ---------------------------------------------------------------------------
__global__ __launch_bounds__(256) void kA(const float* __restrict__ x,
        const float* __restrict__ w1, const float* __restrict__ b1,
        const float* __restrict__ gn_w, const float* __restrict__ gn_b,
        float* __restrict__ ws_xh, float* __restrict__ ws_xw,
        float* __restrict__ ws_scale, float* __restrict__ ws_shift)
{
    const int g = blockIdx.x;
    const int tid = threadIdx.x;
    const float* gx = x + (size_t)g * CG * HW;

    __shared__ float s_row[CG][HH];   // row means per channel
    __shared__ float s_col[CG][WW];   // col means per channel
    __shared__ float s_xh[CG][HH];    // sigmoid gate over rows
    __shared__ float s_xw[CG][WW];    // sigmoid gate over cols
    __shared__ float ls1[CG], ls2[CG];

    // row means: task = (c, row), sum 56 contiguous floats
    for (int t = tid; t < CG * HH; t += 256) {
        int c = t / HH, r = t - (t / HH) * HH;
        const float* p = gx + c * HW + r * WW;
        float s = 0.f;
        #pragma unroll 8
        for (int i = 0; i < WW; ++i) s += p[i];
        s_row[c][r] = s * (1.0f / WW);
    }
    // col means: task = (c, col), stride-56 reads (coalesced across lanes)
    for (int t = tid; t < CG * WW; t += 256) {
        int c = t / WW, col = t - (t / WW) * WW;
        const float* p = gx + c * HW + col;
        float s = 0.f;
        #pragma unroll 8
        for (int i = 0; i < HH; ++i) s += p[i * WW];
        s_col[c][col] = s * (1.0f / HH);
    }
    __syncthreads();

    // 1x1 conv (16x16 channel mix) + bias + sigmoid
    for (int t = tid; t < 2 * CG * HH; t += 256) {
        int hpart = (t < CG * HH);
        int tt = hpart ? t : t - CG * HH;
        int o = tt / HH, i = tt - (tt / HH) * HH;
        float v = b1[o];
        #pragma unroll
        for (int c = 0; c < CG; ++c)
            v += w1[o * CG + c] * (hpart ? s_row[c][i] : s_col[c][i]);
        float sg = 1.f / (1.f + __expf(-v));
        if (hpart) { s_xh[o][i] = sg; ws_xh[(size_t)g * CG * HH + tt] = sg; }
        else       { s_xw[o][i] = sg; ws_xw[(size_t)g * CG * WW + tt] = sg; }
    }
    if (tid < CG) { ls1[tid] = 0.f; ls2[tid] = 0.f; }
    __syncthreads();

    // per-channel sum / sumsq of t = gx * xh * xw
    for (int c = 0; c < CG; ++c) {
        float s1 = 0.f, s2 = 0.f;
        const float* p = gx + c * HW;
        for (int l = tid; l < HW; l += 256) {
            int yy = l / WW, xx = l - yy * WW;
            float t = p[l] * s_xh[c][yy] * s_xw[c][xx];
            s1 += t; s2 += t * t;
        }
        #pragma unroll
        for (int off = 32; off; off >>= 1) {
            s1 += __shfl_down(s1, off);
            s2 += __shfl_down(s2, off);
        }
        if ((tid & 63) == 0) {
            atomicAdd(&ls1[c], s1);
            atomicAdd(&ls2[c], s2);
        }
    }
    __syncthreads();
    if (tid < CG) {
        float mu  = ls1[tid] * (1.0f / HW);
        float var = ls2[tid] * (1.0f / HW) - mu * mu;
        float sc  = gn_w[tid] * rsqrtf(var + EPS);
        float sh  = gn_b[tid] - mu * sc;
        ws_scale[(size_t)g * CG + tid] = sc;
        ws_shift[(size_t)g * CG + tid] = sh;
    }
}

// ---------------------------------------------------------------------------
// Kernel B: 3x3 conv (16 -> 1 out channel per block). Block = (g, o).
// Accumulates a1[o] * x2 into wsum[g][l] (global atomics; a1 = softmax(gn_b)
// is known in advance since x1's spatial mean is exactly gn_b), and the
// complete per-(g,o) spatial sum for a2 via block reduction (plain store).
// ---------------------------------------------------------------------------
__global__ __launch_bounds__(256) void kB(const float* __restrict__ x,
        const float* __restrict__ w3, const float* __restrict__ b3,
        const float* __restrict__ gn_b,
        float* __restrict__ wsum, float* __restrict__ x2sum)
{
    const int bid = blockIdx.x;
    const int g = bid >> 4, o = bid & 15;
    const int tid = threadIdx.x;
    const float* gx = x + (size_t)g * CG * HW;

    // a1[o] = softmax(gn_b)[o]  (uniform across block; scalar math)
    float m = gn_b[0];
    #pragma unroll
    for (int c = 1; c < CG; ++c) m = fmaxf(m, gn_b[c]);
    float den = 0.f, eo = 0.f;
    #pragma unroll
    for (int c = 0; c < CG; ++c) {
        float e = __expf(gn_b[c] - m);
        den += e;
        if (c == o) eo = e;
    }
    const float a1o = eo / den;
    const float b3o = b3[o];

    float lsum = 0.f;
    // 392 strips of 8 pixels: strip s -> row y = s/7, x0 = (s%7)*8
    for (int s = tid; s < 392; s += 256) {
        int y = s / 7, xs = (s - (s / 7) * 7) * 8;
        float acc[8];
        #pragma unroll
        for (int j = 0; j < 8; ++j) acc[j] = b3o;

        for (int ci = 0; ci < CG; ++ci) {
            const float* wp = w3 + (size_t)(o * CG + ci) * 9;
            float wv[9];
            #pragma unroll
            for (int k = 0; k < 9; ++k) wv[k] = wp[k];   // block-uniform -> SGPR
            const float* ip = gx + ci * HW;
            #pragma unroll
            for (int dy = 0; dy < 3; ++dy) {
                int ry = y + dy - 1;
                if (ry < 0 || ry >= HH) continue;        // zero pad rows
                float in[10];
                const float* rp = ip + ry * WW;
                #pragma unroll
                for (int k = 0; k < 10; ++k) {
                    int xc = xs - 1 + k;
                    in[k] = (xc >= 0 && xc < WW) ? rp[xc] : 0.f;  // zero pad cols
                }
                #pragma unroll
                for (int j = 0; j < 8; ++j) {
                    #pragma unroll
                    for (int dx = 0; dx < 3; ++dx)
                        acc[j] += wv[dy * 3 + dx] * in[j + dx];
                }
            }
        }
        float* wp2 = wsum + (size_t)g * HW + y * WW + xs;
        float ss = 0.f;
        #pragma unroll
        for (int j = 0; j < 8; ++j) {
            ss += acc[j];
            atomicAdd(&wp2[j], a1o * acc[j]);
        }
        lsum += ss;
    }

    __shared__ float red[256];
    red[tid] = lsum;
    __syncthreads();
    #pragma unroll
    for (int st = 128; st; st >>= 1) {
        if (tid < st) red[tid] += red[tid + st];
        __syncthreads();
    }
    if (tid == 0) x2sum[(size_t)g * CG + o] = red[0];
}

// ---------------------------------------------------------------------------
// Kernel C: a2 = softmax(mean(x2)); recompute x1 from gx (scale/shift known);
// weights = wsum + sum_c a2[c]*x1[c,l]; out = gx * sigmoid(weights).
// One block per bg-instance.
// ---------------------------------------------------------------------------
__global__ __launch_bounds__(256) void kC(const float* __restrict__ x,
        const float* __restrict__ wsum, const float* __restrict__ x2sum,
        const float* __restrict__ ws_xh, const float* __restrict__ ws_xw,
        const float* __restrict__ ws_scale, const float* __restrict__ ws_shift,
        float* __restrict__ out)
{
    const int g = blockIdx.x;
    const int tid = threadIdx.x;
    const float* gx = x + (size_t)g * CG * HW;
    float* og = out + (size_t)g * CG * HW;

    __shared__ float s_xh[CG][HH], s_xw[CG][WW];
    __shared__ float s_a2[CG], s_sc[CG], s_sh[CG];

    for (int t = tid; t < CG * HH; t += 256)
        s_xh[t / HH][t - (t / HH) * HH] = ws_xh[(size_t)g * CG * HH + t];
    for (int t = tid; t < CG * WW; t += 256)
        s_xw[t / WW][t - (t / WW) * WW] = ws_xw[(size_t)g * CG * WW + t];
    if (tid < CG) {
        s_sc[tid] = ws_scale[(size_t)g * CG + tid];
        s_sh[tid] = ws_shift[(size_t)g * CG + tid];
    }
    if (tid == 0) {
        float mv[CG]; float m = -1e30f;
        #pragma unroll
        for (int c = 0; c < CG; ++c) {
            mv[c] = x2sum[(size_t)g * CG + c] * (1.0f / HW);
            m = fmaxf(m, mv[c]);
        }
        float den = 0.f;
        #pragma unroll
        for (int c = 0; c < CG; ++c) { mv[c] = __expf(mv[c] - m); den += mv[c]; }
        #pragma unroll
        for (int c = 0; c < CG; ++c) s_a2[c] = mv[c] / den;
    }
    __syncthreads();

    for (int l = tid; l < HW; l += 256) {
        int yy = l / WW, xx = l - yy * WW;
        float gv[CG];
        float acc = wsum[(size_t)g * HW + l];
        #pragma unroll
        for (int c = 0; c < CG; ++c) {
            float v = gx[c * HW + l];
            gv[c] = v;
            float t = v * s_xh[c][yy] * s_xw[c][xx];
            acc += s_a2[c] * (s_sc[c] * t + s_sh[c]);
        }
        float sg = 1.f / (1.f + __expf(-acc));
        #pragma unroll
        for (int c = 0; c < CG; ++c) og[c * HW + l] = gv[c] * sg;
    }
}

// ---------------------------------------------------------------------------
extern "C" void kernel_launch(void* const* d_in, const int* in_sizes, int n_in,
                              void* d_out, int out_size, void* d_ws, size_t ws_size,
                              hipStream_t stream)
{
    const float* x    = (const float*)d_in[0];
    const float* w1   = (const float*)d_in[1];
    const float* b1   = (const float*)d_in[2];
    const float* w3   = (const float*)d_in[3];
    const float* b3   = (const float*)d_in[4];
    const float* gn_w = (const float*)d_in[5];
    const float* gn_b = (const float*)d_in[6];
    float* out = (float*)d_out;

    float* ws = (float*)d_ws;
    float* wsum     = ws;                                   // BG*HW
    float* ws_xh    = wsum + (size_t)BG * HW;               // BG*CG*HH
    float* ws_xw    = ws_xh + (size_t)BG * CG * HH;         // BG*CG*WW
    float* ws_scale = ws_xw + (size_t)BG * CG * WW;         // BG*CG
    float* ws_shift = ws_scale + (size_t)BG * CG;           // BG*CG
    float* x2sum    = ws_shift + (size_t)BG * CG;           // BG*CG

    hipMemsetAsync(wsum, 0, (size_t)BG * HW * sizeof(float), stream);
    kA<<<BG, 256, 0, stream>>>(x, w1, b1, gn_w, gn_b, ws_xh, ws_xw, ws_scale, ws_shift);
    kB<<<BG * CG, 256, 0, stream>>>(x, w3, b3, gn_b, wsum, x2sum);
    kC<<<BG, 256, 0, stream>>>(x, wsum, x2sum, ws_xh, ws_xw, ws_scale, ws_shift, out);
}

// Round 2
// 836.758 us; speedup vs baseline: 6.5826x; 6.5826x over previous
//
#include <hip/hip_runtime.h>
#include <math.h>

#define GROUPS 32
#define CG 16
#define HH 56
#define WW 56
#define HW (HH*WW)          // 3136
#define BG 1024             // B*GROUPS
#define EPS 1e-5f

// ---------------------------------------------------------------------------
// Kernel A: per-instance directional pooling -> 1x1 channel mix -> sigmoid
// gates (xh, xw); per-channel mean/var of t = gx*xh*xw -> scale/shift; and
// ANALYTIC x2sum: spatial sum of SAME-pad 3x3 conv = sum_k w[k]*T(k), where
// T(dy,dx) = S - R(dy) - C(dx) + corner, built from the row/col sums we
// already have. One block per bg-instance.
// ---------------------------------------------------------------------------
__global__ __launch_bounds__(256) void kA(const float* __restrict__ x,
        const float* __restrict__ w1, const float* __restrict__ b1,
        const float* __restrict__ w3, const float* __restrict__ b3,
        const float* __restrict__ gn_w, const float* __restrict__ gn_b,
        float* __restrict__ ws_xh, float* __restrict__ ws_xw,
        float* __restrict__ ws_scale, float* __restrict__ ws_shift,
        float* __restrict__ x2sum)
{
    const int g = blockIdx.x;
    const int tid = threadIdx.x;
    const float* gx = x + (size_t)g * CG * HW;

    __shared__ float s_row[CG][HH];   // row means per channel
    __shared__ float s_col[CG][WW];   // col means per channel
    __shared__ float s_xh[CG][HH];    // sigmoid gate over rows
    __shared__ float s_xw[CG][WW];    // sigmoid gate over cols
    __shared__ float ls1[CG], ls2[CG];

    // row means: task = (c, row), sum 56 contiguous floats
    for (int t = tid; t < CG * HH; t += 256) {
        int c = t / HH, r = t - (t / HH) * HH;
        const float* p = gx + c * HW + r * WW;
        float s = 0.f;
        #pragma unroll 8
        for (int i = 0; i < WW; ++i) s += p[i];
        s_row[c][r] = s * (1.0f / WW);
    }
    // col means: task = (c, col), stride-56 reads (coalesced across lanes)
    for (int t = tid; t < CG * WW; t += 256) {
        int c = t / WW, col = t - (t / WW) * WW;
        const float* p = gx + c * HW + col;
        float s = 0.f;
        #pragma unroll 8
        for (int i = 0; i < HH; ++i) s += p[i * WW];
        s_col[c][col] = s * (1.0f / HH);
    }
    __syncthreads();

    // 1x1 conv (16x16 channel mix) + bias + sigmoid
    for (int t = tid; t < 2 * CG * HH; t += 256) {
        int hpart = (t < CG * HH);
        int tt = hpart ? t : t - CG * HH;
        int o = tt / HH, i = tt - (tt / HH) * HH;
        float v = b1[o];
        #pragma unroll
        for (int c = 0; c < CG; ++c)
            v += w1[o * CG + c] * (hpart ? s_row[c][i] : s_col[c][i]);
        float sg = 1.f / (1.f + __expf(-v));
        if (hpart) { s_xh[o][i] = sg; ws_xh[(size_t)g * CG * HH + tt] = sg; }
        else       { s_xw[o][i] = sg; ws_xw[(size_t)g * CG * WW + tt] = sg; }
    }

    // analytic x2sum: thread o computes spatial sum of conv output channel o
    if (tid < CG) {
        ls1[tid] = 0.f; ls2[tid] = 0.f;
        const int o = tid;
        float acc = (float)HW * b3[o];
        for (int c = 0; c < CG; ++c) {
            float S = 0.f;
            #pragma unroll
            for (int r = 0; r < HH; ++r) S += s_row[c][r];
            S *= (float)WW;
            // excluded-row sums: dy=0 -> row 55, dy=2 -> row 0
            float R0 = (float)WW * s_row[c][HH - 1];
            float R2 = (float)WW * s_row[c][0];
            // excluded-col sums: dx=0 -> col 55, dx=2 -> col 0
            float C0 = (float)HH * s_col[c][WW - 1];
            float C2 = (float)HH * s_col[c][0];
            const float* p = gx + c * HW;
            float e00 = p[0], e0N = p[WW - 1];
            float eN0 = p[(HH - 1) * WW], eNN = p[(HH - 1) * WW + WW - 1];
            const float* wp = w3 + (size_t)(o * CG + c) * 9;
            #pragma unroll
            for (int dy = 0; dy < 3; ++dy) {
                float Rv = (dy == 0) ? R0 : (dy == 2 ? R2 : 0.f);
                #pragma unroll
                for (int dx = 0; dx < 3; ++dx) {
                    float Cv = (dx == 0) ? C0 : (dx == 2 ? C2 : 0.f);
                    float T = S - Rv - Cv;
                    if (dy != 1 && dx != 1)
                        T += (dy == 0) ? ((dx == 0) ? eNN : eN0)
                                       : ((dx == 0) ? e0N : e00);
                    acc += wp[dy * 3 + dx] * T;
                }
            }
        }
        x2sum[(size_t)g * CG + o] = acc;
    }
    __syncthreads();

    // per-channel sum / sumsq of t = gx * xh * xw
    for (int c = 0; c < CG; ++c) {
        float s1 = 0.f, s2 = 0.f;
        const float* p = gx + c * HW;
        for (int l = tid; l < HW; l += 256) {
            int yy = l / WW, xx = l - yy * WW;
            float t = p[l] * s_xh[c][yy] * s_xw[c][xx];
            s1 += t; s2 += t * t;
        }
        #pragma unroll
        for (int off = 32; off; off >>= 1) {
            s1 += __shfl_down(s1, off);
            s2 += __shfl_down(s2, off);
        }
        if ((tid & 63) == 0) {
            atomicAdd(&ls1[c], s1);
            atomicAdd(&ls2[c], s2);
        }
    }
    __syncthreads();
    if (tid < CG) {
        float mu  = ls1[tid] * (1.0f / HW);
        float var = ls2[tid] * (1.0f / HW) - mu * mu;
        float sc  = gn_w[tid] * rsqrtf(var + EPS);
        float sh  = gn_b[tid] - mu * sc;
        ws_scale[(size_t)g * CG + tid] = sc;
        ws_shift[(size_t)g * CG + tid] = sh;
    }
}

// ---------------------------------------------------------------------------
// Kernel B2: a1-folded 3x3 conv, 16 -> 1 "channel" per instance.
// wa1[ci][k] = sum_o a1[o]*w3[o][ci][k]; wsum = wa1 (x) gx + sum_o a1[o]b3[o].
// One block per bg-instance; plain stores, no atomics.
// ---------------------------------------------------------------------------
__global__ __launch_bounds__(256) void kB2(const float* __restrict__ x,
        const float* __restrict__ w3, const float* __restrict__ b3,
        const float* __restrict__ gn_b, float* __restrict__ wsum)
{
    const int g = blockIdx.x;
    const int tid = threadIdx.x;
    const float* gx = x + (size_t)g * CG * HW;

    __shared__ float s_wa[CG][9];
    __shared__ float s_ab;

    if (tid < CG * 9 + 1) {
        // a1 = softmax(gn_b) (x1's spatial mean is exactly gn_b)
        float m = gn_b[0];
        #pragma unroll
        for (int c = 1; c < CG; ++c) m = fmaxf(m, gn_b[c]);
        float a1[CG]; float den = 0.f;
        #pragma unroll
        for (int c = 0; c < CG; ++c) { a1[c] = __expf(gn_b[c] - m); den += a1[c]; }
        float inv = 1.f / den;
        if (tid < CG * 9) {
            int ci = tid / 9, k = tid - (tid / 9) * 9;
            float s = 0.f;
            #pragma unroll
            for (int o = 0; o < CG; ++o) s += a1[o] * w3[(size_t)(o * CG + ci) * 9 + k];
            s_wa[ci][k] = s * inv;
        } else {
            float s = 0.f;
            #pragma unroll
            for (int o = 0; o < CG; ++o) s += a1[o] * b3[o];
            s_ab = s * inv;
        }
    }
    __syncthreads();

    // 392 strips of 8 pixels: strip s -> row y = s/7, x0 = (s%7)*8
    for (int s = tid; s < 392; s += 256) {
        int y = s / 7, xs = (s - (s / 7) * 7) * 8;
        float acc[8];
        float ab = s_ab;
        #pragma unroll
        for (int j = 0; j < 8; ++j) acc[j] = ab;

        for (int ci = 0; ci < CG; ++ci) {
            const float* ip = gx + ci * HW;
            #pragma unroll
            for (int dy = 0; dy < 3; ++dy) {
                int ry = y + dy - 1;
                if (ry < 0 || ry >= HH) continue;        // zero pad rows
                float in[10];
                const float* rp = ip + ry * WW;
                #pragma unroll
                for (int k = 0; k < 10; ++k) {
                    int xc = xs - 1 + k;
                    in[k] = (xc >= 0 && xc < WW) ? rp[xc] : 0.f;  // zero pad cols
                }
                #pragma unroll
                for (int j = 0; j < 8; ++j)
                    acc[j] += s_wa[ci][dy * 3 + 0] * in[j]
                            + s_wa[ci][dy * 3 + 1] * in[j + 1]
                            + s_wa[ci][dy * 3 + 2] * in[j + 2];
            }
        }
        float* wp2 = wsum + (size_t)g * HW + y * WW + xs;
        #pragma unroll
        for (int j = 0; j < 8; ++j) wp2[j] = acc[j];
    }
}

// ---------------------------------------------------------------------------
// Kernel C: a2 = softmax(mean(x2)); recompute x1 from gx (scale/shift known);
// weights = wsum + sum_c a2[c]*x1[c,l]; out = gx * sigmoid(weights).
// One block per bg-instance.
// ---------------------------------------------------------------------------
__global__ __launch_bounds__(256) void kC(const float* __restrict__ x,
        const float* __restrict__ wsum, const float* __restrict__ x2sum,
        const float* __restrict__ ws_xh, const float* __restrict__ ws_xw,
        const float* __restrict__ ws_scale, const float* __restrict__ ws_shift,
        float* __restrict__ out)
{
    const int g = blockIdx.x;
    const int tid = threadIdx.x;
    const float* gx = x + (size_t)g * CG * HW;
    float* og = out + (size_t)g * CG * HW;

    __shared__ float s_xh[CG][HH], s_xw[CG][WW];
    __shared__ float s_a2[CG], s_sc[CG], s_sh[CG];

    for (int t = tid; t < CG * HH; t += 256)
        s_xh[t / HH][t - (t / HH) * HH] = ws_xh[(size_t)g * CG * HH + t];
    for (int t = tid; t < CG * WW; t += 256)
        s_xw[t / WW][t - (t / WW) * WW] = ws_xw[(size_t)g * CG * WW + t];
    if (tid < CG) {
        s_sc[tid] = ws_scale[(size_t)g * CG + tid];
        s_sh[tid] = ws_shift[(size_t)g * CG + tid];
    }
    if (tid == 0) {
        float mv[CG]; float m = -1e30f;
        #pragma unroll
        for (int c = 0; c < CG; ++c) {
            mv[c] = x2sum[(size_t)g * CG + c] * (1.0f / HW);
            m = fmaxf(m, mv[c]);
        }
        float den = 0.f;
        #pragma unroll
        for (int c = 0; c < CG; ++c) { mv[c] = __expf(mv[c] - m); den += mv[c]; }
        #pragma unroll
        for (int c = 0; c < CG; ++c) s_a2[c] = mv[c] / den;
    }
    __syncthreads();

    for (int l = tid; l < HW; l += 256) {
        int yy = l / WW, xx = l - yy * WW;
        float gv[CG];
        float acc = wsum[(size_t)g * HW + l];
        #pragma unroll
        for (int c = 0; c < CG; ++c) {
            float v = gx[c * HW + l];
            gv[c] = v;
            float t = v * s_xh[c][yy] * s_xw[c][xx];
            acc += s_a2[c] * (s_sc[c] * t + s_sh[c]);
        }
        float sg = 1.f / (1.f + __expf(-acc));
        #pragma unroll
        for (int c = 0; c < CG; ++c) og[c * HW + l] = gv[c] * sg;
    }
}

// ---------------------------------------------------------------------------
extern "C" void kernel_launch(void* const* d_in, const int* in_sizes, int n_in,
                              void* d_out, int out_size, void* d_ws, size_t ws_size,
                              hipStream_t stream)
{
    const float* x    = (const float*)d_in[0];
    const float* w1   = (const float*)d_in[1];
    const float* b1   = (const float*)d_in[2];
    const float* w3   = (const float*)d_in[3];
    const float* b3   = (const float*)d_in[4];
    const float* gn_w = (const float*)d_in[5];
    const float* gn_b = (const float*)d_in[6];
    float* out = (float*)d_out;

    float* ws = (float*)d_ws;
    float* wsum     = ws;                                   // BG*HW
    float* ws_xh    = wsum + (size_t)BG * HW;               // BG*CG*HH
    float* ws_xw    = ws_xh + (size_t)BG * CG * HH;         // BG*CG*WW
    float* ws_scale = ws_xw + (size_t)BG * CG * WW;         // BG*CG
    float* ws_shift = ws_scale + (size_t)BG * CG;           // BG*CG
    float* x2sum    = ws_shift + (size_t)BG * CG;           // BG*CG

    kA<<<BG, 256, 0, stream>>>(x, w1, b1, w3, b3, gn_w, gn_b,
                               ws_xh, ws_xw, ws_scale, ws_shift, x2sum);
    kB2<<<BG, 256, 0, stream>>>(x, w3, b3, gn_b, wsum);
    kC<<<BG, 256, 0, stream>>>(x, wsum, x2sum, ws_xh, ws_xw, ws_scale, ws_shift, out);
}